// Round 13
// baseline (47.834 us; speedup 1.0000x reference)
//
#include <hip/hip_runtime.h>
#include <hip/hip_bf16.h>
#include <math.h>

#define COLORS 10
#define NB 32
#define H 128
#define W 128
#define NS 120          // 11*11 - 1 shifts
#define HW (H*W)
#define NT 16           // strips (match), 8 rows each
#define DR2 18          // 8 + 10 padded rows
#define DINW 12         // padded D row stride in u32 (48B)
#define AR 18           // accum staged rows (8-row tile + 10)

typedef unsigned char u8;
typedef unsigned int u32;
typedef unsigned long long u64;
typedef float f32x4 __attribute__((ext_vector_type(4)));
typedef short bf16x8 __attribute__((ext_vector_type(8)));

// ---------------- kernel 1: per-(b,strip) bitplane popcount match ----------------
// 512 blocks (16 strips x 32 b) x 256 thr (4 waves). dx-sharing compute:
// thread = (dyIdx 0..10, ch 0..1, y 0..7) -> 176 active; regs hold D/O rows.
__global__ __launch_bounds__(256, 4) void match_strip(
    const int* __restrict__ demo_in, const int* __restrict__ demo_out,
    const float* __restrict__ clw, float* __restrict__ mpart)
{
    __shared__ __align__(16) u32 din_p[COLORS][DR2][DINW];   // 8640 B
    __shared__ __align__(16) u32 dout_p[COLORS][8][4];       // 1280 B
    __shared__ float wexp[COLORS];

    int t = threadIdx.x;
    int strip = blockIdx.x;
    int b = blockIdx.y;
    int wave = t >> 6, lane = t & 63;
    int y0 = strip * 8;

    if (t < COLORS) wexp[t] = __expf(clw[t]);

    const int* di = demo_in  + b * HW;
    const int* dd = demo_out + b * HW;

    for (int r = wave; r < DR2; r += 4) {
        int gy = y0 - 5 + r;
        bool ok = (gy >= 0 && gy < H);
        int v0 = 0, v1 = 0;
        if (ok) { v0 = di[gy * W + lane]; v1 = di[gy * W + 64 + lane]; }
        #pragma unroll
        for (int c = 0; c < COLORS; c++) {
            u64 h0 = __ballot(v0 == c);
            u64 h1 = __ballot(v1 == c);
            u64 P0, P1, P2;
            if (!ok) {
                P0 = (c == 0) ? ~0ull : 0ull;
                P1 = P0;
                P2 = (c == 0) ? 0x3FFull : 0ull;
            } else {
                u64 lm = (c == 0) ? 0x1Full  : 0ull;
                u64 rm = (c == 0) ? 0x3E0ull : 0ull;
                P0 = (h0 << 5) | lm;
                P1 = (h0 >> 59) | (h1 << 5);
                P2 = (h1 >> 59) | rm;
            }
            if (lane == 0) {
                *reinterpret_cast<uint4*>(&din_p[c][r][0]) =
                    make_uint4((u32)P0, (u32)(P0 >> 32), (u32)P1, (u32)(P1 >> 32));
                *reinterpret_cast<uint4*>(&din_p[c][r][4]) =
                    make_uint4((u32)P2, 0u, 0u, 0u);
            }
        }
    }
    for (int r = wave; r < 8; r += 4) {
        int gy = y0 + r;
        int v0 = dd[gy * W + lane], v1 = dd[gy * W + 64 + lane];
        #pragma unroll
        for (int c = 0; c < COLORS; c++) {
            u64 h0 = __ballot(v0 == c);
            u64 h1 = __ballot(v1 == c);
            if (lane == 0)
                *reinterpret_cast<uint4*>(&dout_p[c][r][0]) =
                    make_uint4((u32)h0, (u32)(h0 >> 32), (u32)h1, (u32)(h1 >> 32));
        }
    }
    __syncthreads();

    // compute: dyIdx = t>>4, ch = (t>>3)&1, y = t&7
    float acc[11];
    #pragma unroll
    for (int i = 0; i < 11; i++) acc[i] = 0.f;

    if (t < 176) {
        int dyIdx = t >> 4;
        int ch    = (t >> 3) & 1;
        int y     = t & 7;
        int r     = y - dyIdx + 10;          // in [0,17]

        #pragma unroll
        for (int cc = 0; cc < 5; cc++) {
            int c = ch * 5 + cc;
            const u32* dr = &din_p[c][r][0];
            u32 d0 = dr[0], d1 = dr[1], d2 = dr[2], d3 = dr[3], d4 = dr[4];
            const u32* orw = &dout_p[c][y][0];
            u32 o0 = orw[0], o1 = orw[1], o2 = orw[2], o3 = orw[3];
            float wgt = wexp[c];
            #pragma unroll
            for (int dxi = 0; dxi < 11; dxi++) {
                int k = 10 - dxi;
                u32 s0 = __builtin_amdgcn_alignbit(d1, d0, k);
                u32 s1 = __builtin_amdgcn_alignbit(d2, d1, k);
                u32 s2 = __builtin_amdgcn_alignbit(d3, d2, k);
                u32 s3 = __builtin_amdgcn_alignbit(d4, d3, k);
                int cnt = __popc(s0 & o0) + __popc(s1 & o1)
                        + __popc(s2 & o2) + __popc(s3 & o3);
                acc[dxi] += wgt * (float)cnt;
            }
        }
    }

    // reduce over the 16-lane (ch x y) group
    #pragma unroll
    for (int dxi = 0; dxi < 11; dxi++) {
        float v = acc[dxi];
        v += __shfl_down(v, 8, 16);
        v += __shfl_down(v, 4, 16);
        v += __shfl_down(v, 2, 16);
        v += __shfl_down(v, 1, 16);
        acc[dxi] = v;
    }
    if ((t & 15) == 0 && t < 176) {
        int dyIdx = t >> 4;
        #pragma unroll
        for (int dxi = 0; dxi < 11; dxi++) {
            int lin = dyIdx * 11 + dxi;
            if (lin == 60) continue;         // (0,0) excluded
            int s = lin - (lin > 60);
            mpart[(b * NS + s) * NT + strip] = acc[dxi];
        }
    }
}

// -------- kernel 2: fused softmax + A-table + MFMA, 256 thr (4 waves) --------
// 512 blocks (16 ytiles x 32 b); wave w does 2 column slices x0=(w*2+ti)*16.
__global__ __launch_bounds__(256, 4) void accum_fused(
    const int* __restrict__ query_in, const float* __restrict__ mpart,
    const float* __restrict__ logit_scale, float* __restrict__ out)
{
    __shared__ u8  qs[AR][144];                    // 2592 B
    __shared__ float sm[NS];
    __shared__ unsigned short abf[128];
    __shared__ __align__(16) u32 Agl[11][64][4];   // 11264 B

    int t  = threadIdx.x;
    int y0 = blockIdx.x * 8;
    int b  = blockIdx.y;
    const int* q = query_in + b * HW;

    // ---- staging: 648 packed words over 256 threads (3 passes) ----
    u32 pk0 = 0, pk1 = 0, pk2 = 0;
    #pragma unroll
    for (int e = 0; e < 4; e++) {
        int idx = t * 4 + e;
        int r = idx / 144, p = idx - r * 144;
        int gy = y0 - 5 + r;
        bool ok = (gy >= 0) & (gy < H) & (p >= 5) & (p < 133);
        int cy = gy < 0 ? 0 : (gy > 127 ? 127 : gy);
        int cx = p < 5 ? 0 : (p > 132 ? 127 : p - 5);
        int v = q[cy * W + cx];
        pk0 |= (u32)(ok ? v : 0) << (8 * e);
    }
    #pragma unroll
    for (int e = 0; e < 4; e++) {
        int idx = (t + 256) * 4 + e;
        int r = idx / 144, p = idx - r * 144;
        int gy = y0 - 5 + r;
        bool ok = (gy >= 0) & (gy < H) & (p >= 5) & (p < 133);
        int cy = gy < 0 ? 0 : (gy > 127 ? 127 : gy);
        int cx = p < 5 ? 0 : (p > 132 ? 127 : p - 5);
        int v = q[cy * W + cx];
        pk1 |= (u32)(ok ? v : 0) << (8 * e);
    }
    if (t < 648 - 512) {
        #pragma unroll
        for (int e = 0; e < 4; e++) {
            int idx = (t + 512) * 4 + e;
            int r = idx / 144, p = idx - r * 144;
            int gy = y0 - 5 + r;
            bool ok = (gy >= 0) & (gy < H) & (p >= 5) & (p < 133);
            int cy = gy < 0 ? 0 : (gy > 127 ? 127 : gy);
            int cx = p < 5 ? 0 : (p > 132 ? 127 : p - 5);
            int v = q[cy * W + cx];
            pk2 |= (u32)(ok ? v : 0) << (8 * e);
        }
    }

    // ---- phase B: strip reduction (16 strips per shift) ----
    float scale = fminf(__expf(logit_scale[0]), 100.0f) * (1.0f / 128.0f);
    if (t < NS) {
        const float* mp = mpart + (t + b * NS) * NT;
        float4 v0 = *reinterpret_cast<const float4*>(mp);
        float4 v1 = *reinterpret_cast<const float4*>(mp + 4);
        float4 v2 = *reinterpret_cast<const float4*>(mp + 8);
        float4 v3 = *reinterpret_cast<const float4*>(mp + 12);
        sm[t] = (v0.x + v0.y + v0.z + v0.w + v1.x + v1.y + v1.z + v1.w
               + v2.x + v2.y + v2.z + v2.w + v3.x + v3.y + v3.z + v3.w) * scale;
    }

    ((u32*)qs)[t] = pk0;
    ((u32*)qs)[t + 256] = pk1;
    if (t < 648 - 512) ((u32*)qs)[t + 512] = pk2;
    __syncthreads();

    if (t < 64) {
        float s0 = sm[t];
        float s1 = (t + 64 < NS) ? sm[t + 64] : -INFINITY;
        float m = fmaxf(s0, s1);
        for (int off = 32; off > 0; off >>= 1) m = fmaxf(m, __shfl_xor(m, off, 64));
        float e0 = __expf(s0 - m);
        float e1 = (t + 64 < NS) ? __expf(s1 - m) : 0.f;
        float sum = e0 + e1;
        for (int off = 32; off > 0; off >>= 1) sum += __shfl_xor(sum, off, 64);
        float inv = 1.0f / sum;
        sm[t] = e0 * inv;
        if (t + 64 < NS) sm[t + 64] = e1 * inv;
    }
    __syncthreads();
    if (t < 128) {
        unsigned short v = 0;
        if (t < 121 && t != 60) {
            int si = t - (t > 60);
            __hip_bfloat16 hb = __float2bfloat16(sm[si]);
            v = *reinterpret_cast<unsigned short*>(&hb);
        }
        abf[t] = v;
    }
    __syncthreads();

    // ---- cooperative A-fragment table: 704 entries over 256 threads ----
    #pragma unroll
    for (int base = 0; base < 768; base += 256) {
        int e = t + base;
        if (e < 704) {
            int st = e >> 6, l = e & 63;
            int mrow = l & 15, g8 = (l >> 4) * 8;
            #pragma unroll
            for (int p = 0; p < 4; p++) {
                int j0 = mrow + 10 - (g8 + p * 2);
                int j1 = j0 - 1;
                int i0 = (j0 >= 0 && j0 <= 10) ? (10 - st) * 11 + j0 : 121;
                int i1 = (j1 >= 0 && j1 <= 10) ? (10 - st) * 11 + j1 : 121;
                Agl[st][l][p] = (u32)abf[i0] | ((u32)abf[i1] << 16);
            }
        }
    }
    __syncthreads();

    // ---- MFMA: wave w -> 2 column slices, 8-row sliding B-window each ----
    int lane = t & 63, w = t >> 6;
    int c = lane & 15, g = lane >> 4;

    #define BUILD_B(r, x0) ({                                                    \
        u64 eight = *reinterpret_cast<const u64*>(&qs[(r)][(x0) + 8 * g]);       \
        u32 lo = (u32)eight, hi = (u32)(eight >> 32);                            \
        u32 b0 = ((int)(lo & 255) == c ? 0x3F80u : 0u)                           \
               | ((int)((lo >> 8)  & 255) == c ? 0x3F800000u : 0u);              \
        u32 b1 = ((int)((lo >> 16) & 255) == c ? 0x3F80u : 0u)                   \
               | ((int)((lo >> 24) & 255) == c ? 0x3F800000u : 0u);              \
        u32 b2 = ((int)(hi & 255) == c ? 0x3F80u : 0u)                           \
               | ((int)((hi >> 8)  & 255) == c ? 0x3F800000u : 0u);              \
        u32 b3 = ((int)((hi >> 16) & 255) == c ? 0x3F80u : 0u)                   \
               | ((int)((hi >> 24) & 255) == c ? 0x3F800000u : 0u);              \
        make_uint4(b0, b1, b2, b3); })

    #pragma unroll
    for (int ti = 0; ti < 2; ti++) {
        int x0 = (w * 2 + ti) * 16;

        uint4 bf[8];
        #pragma unroll
        for (int r = 0; r < 7; r++) bf[r & 7] = BUILD_B(r, x0);

        f32x4 acc0[4], acc1[4];
        #pragma unroll
        for (int j = 0; j < 4; j++) { acc0[j] = (f32x4){0,0,0,0}; acc1[j] = (f32x4){0,0,0,0}; }

        #pragma unroll
        for (int st = 0; st < 11; st++) {
            bf[(st + 7) & 7] = BUILD_B(st + 7, x0);
            uint4 a4 = *reinterpret_cast<const uint4*>(&Agl[st][lane][0]);
            union { uint4 u; bf16x8 v; } A; A.u = a4;
            #pragma unroll
            for (int j = 0; j < 4; j++) {
                union { uint4 u; bf16x8 v; } B0, B1;
                B0.u = bf[(st + j) & 7];
                B1.u = bf[(st + 4 + j) & 7];
                acc0[j] = __builtin_amdgcn_mfma_f32_16x16x32_bf16(A.v, B0.v, acc0[j], 0, 0, 0);
                acc1[j] = __builtin_amdgcn_mfma_f32_16x16x32_bf16(A.v, B1.v, acc1[j], 0, 0, 0);
            }
        }

        if (c < COLORS) {
            #pragma unroll
            for (int j = 0; j < 4; j++) {
                float* ob0 = out + (((size_t)b * COLORS + c) * H + (y0 + j)) * W + x0 + 4 * g;
                float4 r0;
                r0.x = __logf(fmaxf(acc0[j][0], 1e-6f));
                r0.y = __logf(fmaxf(acc0[j][1], 1e-6f));
                r0.z = __logf(fmaxf(acc0[j][2], 1e-6f));
                r0.w = __logf(fmaxf(acc0[j][3], 1e-6f));
                *reinterpret_cast<float4*>(ob0) = r0;
                float* ob1 = out + (((size_t)b * COLORS + c) * H + (y0 + 4 + j)) * W + x0 + 4 * g;
                float4 r1;
                r1.x = __logf(fmaxf(acc1[j][0], 1e-6f));
                r1.y = __logf(fmaxf(acc1[j][1], 1e-6f));
                r1.z = __logf(fmaxf(acc1[j][2], 1e-6f));
                r1.w = __logf(fmaxf(acc1[j][3], 1e-6f));
                *reinterpret_cast<float4*>(ob1) = r1;
            }
        }
    }
    #undef BUILD_B
}

// ----------------------- legacy fallback (tiny ws) -----------------------
__global__ __launch_bounds__(256) void match_kernel(
    const int* __restrict__ demo_in, const int* __restrict__ demo_out,
    const float* __restrict__ clw, float* __restrict__ match)
{
    int blk = blockIdx.x;
    int b = blk / NS;
    int s = blk % NS;
    int lin = s + (s >= 60 ? 1 : 0);
    int dy = lin / 11 - 5, dx = lin % 11 - 5;

    __shared__ float wexp[COLORS];
    int tid = threadIdx.x;
    if (tid < COLORS) wexp[tid] = expf(clw[tid]);
    __syncthreads();

    const int* __restrict__ din  = demo_in  + b * HW;
    const int* __restrict__ dout = demo_out + b * HW;

    float partial = 0.f;
    for (int i = tid; i < HW; i += 256) {
        int yy = i >> 7, xx = i & 127;
        int co = dout[i];
        int sy = yy - dy, sx = xx - dx;
        int v = 0;
        if (sy >= 0 && sy < H && sx >= 0 && sx < W) v = din[sy * W + sx];
        if (v == co) partial += wexp[co];
    }
    for (int off = 32; off > 0; off >>= 1) partial += __shfl_down(partial, off, 64);
    __shared__ float wsum[4];
    if ((tid & 63) == 0) wsum[tid >> 6] = partial;
    __syncthreads();
    if (tid == 0) match[blk] = wsum[0] + wsum[1] + wsum[2] + wsum[3];
}

__global__ __launch_bounds__(64) void softmax_kernel(
    const float* __restrict__ match, const float* __restrict__ logit_scale,
    float* __restrict__ attention)
{
    int b = blockIdx.x;
    int lane = threadIdx.x;
    float scale = fminf(expf(logit_scale[0]), 100.0f) / sqrtf((float)HW);
    int i0 = lane, i1 = lane + 64;
    float s0 = match[b * NS + i0] * scale;
    float s1 = (i1 < NS) ? match[b * NS + i1] * scale : -INFINITY;
    float m = fmaxf(s0, s1);
    for (int off = 32; off > 0; off >>= 1) m = fmaxf(m, __shfl_xor(m, off, 64));
    float e0 = expf(s0 - m);
    float e1 = (i1 < NS) ? expf(s1 - m) : 0.f;
    float sum = e0 + e1;
    for (int off = 32; off > 0; off >>= 1) sum += __shfl_xor(sum, off, 64);
    float inv = 1.0f / sum;
    attention[b * NS + i0] = e0 * inv;
    if (i1 < NS) attention[b * NS + i1] = e1 * inv;
}

__global__ __launch_bounds__(128) void accum_kernel(
    const int* __restrict__ query_in, const float* __restrict__ attention,
    float* __restrict__ out)
{
    int blk = blockIdx.x;
    int b = blk >> 7;
    int y = blk & 127;
    int x = threadIdx.x;

    __shared__ float att[NS];
    if (threadIdx.x < NS) att[threadIdx.x] = attention[b * NS + threadIdx.x];
    __syncthreads();

    const int* __restrict__ q = query_in + b * HW;
    float acc[COLORS];
    #pragma unroll
    for (int c = 0; c < COLORS; c++) acc[c] = 0.f;

    #pragma unroll 4
    for (int s = 0; s < NS; s++) {
        int lin = s + (s >= 60 ? 1 : 0);
        int dy = lin / 11 - 5, dx = lin % 11 - 5;
        int sy = y - dy, sx = x - dx;
        int v = 0;
        if (sy >= 0 && sy < H && sx >= 0 && sx < W) v = q[sy * W + sx];
        float a = att[s];
        #pragma unroll
        for (int c = 0; c < COLORS; c++) acc[c] += (v == c) ? a : 0.f;
    }
    float* __restrict__ ob = out + (size_t)b * COLORS * HW + y * W + x;
    #pragma unroll
    for (int c = 0; c < COLORS; c++) ob[c * HW] = __logf(fmaxf(acc[c], 1e-6f));
}

extern "C" void kernel_launch(void* const* d_in, const int* in_sizes, int n_in,
                              void* d_out, int out_size, void* d_ws, size_t ws_size,
                              hipStream_t stream) {
    const int*   demo_in     = (const int*)d_in[0];
    const int*   demo_out    = (const int*)d_in[1];
    const int*   query_in    = (const int*)d_in[2];
    const float* clw         = (const float*)d_in[3];
    const float* logit_scale = (const float*)d_in[4];
    float* out = (float*)d_out;

    size_t needed = (size_t)NB * NS * NT * sizeof(float);   // 245760 B

    if (ws_size >= needed) {
        float* mpart = (float*)d_ws;
        match_strip<<<dim3(NT, NB), 256, 0, stream>>>(demo_in, demo_out, clw, mpart);
        accum_fused<<<dim3(H / 8, NB), 256, 0, stream>>>(query_in, mpart, logit_scale, out);
    } else {
        float* match = (float*)d_ws;
        float* att   = match + NB * NS;
        match_kernel<<<NB * NS, 256, 0, stream>>>(demo_in, demo_out, clw, match);
        softmax_kernel<<<NB, 64, 0, stream>>>(match, logit_scale, att);
        accum_kernel<<<NB * H, 128, 0, stream>>>(query_in, att, out);
    }
}

// Round 14
// 32.991 us; speedup vs baseline: 1.4499x; 1.4499x over previous
//
#include <hip/hip_runtime.h>
#include <hip/hip_bf16.h>
#include <math.h>

#define COLORS 10
#define NB 32
#define H 128
#define W 128
#define NS 120          // 11*11 - 1 shifts
#define HW (H*W)
#define SH 16           // rows per match strip
#define DROWS 26        // SH + 10 padded rows
#define DINW 12         // padded D row stride in u32 (48B)
#define MSLOT 16        // mpart slots per (b,s): 8 strips x 2 color-halves
#define AR 18           // accum staged rows (8-row tile + 10)

typedef unsigned char u8;
typedef unsigned int u32;
typedef unsigned long long u64;
typedef float f32x4 __attribute__((ext_vector_type(4)));
typedef short bf16x8 __attribute__((ext_vector_type(8)));

// ------------- kernel 1: color-split bitplane popcount match -------------
// 512 blocks = (strip 0..7, b*2+ch) x 512 thr -> 2 blocks/CU. Each block
// builds planes for ONLY its 5 colors (half the ballots/LDS, no redundancy);
// compute threads = (dyIdx 0..10, y 0..15), dx-sharing in registers.
__global__ __launch_bounds__(512) void match_strip(
    const int* __restrict__ demo_in, const int* __restrict__ demo_out,
    const float* __restrict__ clw, float* __restrict__ mpart)
{
    __shared__ __align__(16) u32 din_p[5][DROWS][DINW];   // 6240 B
    __shared__ __align__(16) u32 dout_p[5][SH][4];        // 1280 B
    __shared__ float wexp5[5];

    int t = threadIdx.x;
    int strip = blockIdx.x;          // 0..7
    int bc = blockIdx.y;             // 0..63
    int b = bc >> 1, ch = bc & 1;
    int wave = t >> 6, lane = t & 63;
    int y0 = strip * SH;

    if (t < 5) wexp5[t] = __expf(clw[ch * 5 + t]);

    const int* di = demo_in  + b * HW;
    const int* dd = demo_out + b * HW;

    for (int r = wave; r < DROWS; r += 8) {
        int gy = y0 - 5 + r;
        bool ok = (gy >= 0 && gy < H);
        int v0 = 0, v1 = 0;
        if (ok) { v0 = di[gy * W + lane]; v1 = di[gy * W + 64 + lane]; }
        #pragma unroll
        for (int cc = 0; cc < 5; cc++) {
            int c = ch * 5 + cc;
            u64 h0 = __ballot(v0 == c);
            u64 h1 = __ballot(v1 == c);
            u64 P0, P1, P2;
            if (!ok) {                       // OOB row -> color 0 everywhere
                P0 = (c == 0) ? ~0ull : 0ull;
                P1 = P0;
                P2 = (c == 0) ? 0x3FFull : 0ull;
            } else {
                u64 lm = (c == 0) ? 0x1Full  : 0ull;
                u64 rm = (c == 0) ? 0x3E0ull : 0ull;
                P0 = (h0 << 5) | lm;
                P1 = (h0 >> 59) | (h1 << 5);
                P2 = (h1 >> 59) | rm;
            }
            if (lane == 0) {
                *reinterpret_cast<uint4*>(&din_p[cc][r][0]) =
                    make_uint4((u32)P0, (u32)(P0 >> 32), (u32)P1, (u32)(P1 >> 32));
                *reinterpret_cast<uint4*>(&din_p[cc][r][4]) =
                    make_uint4((u32)P2, 0u, 0u, 0u);
            }
        }
    }
    for (int r = wave; r < SH; r += 8) {
        int gy = y0 + r;
        int v0 = dd[gy * W + lane], v1 = dd[gy * W + 64 + lane];
        #pragma unroll
        for (int cc = 0; cc < 5; cc++) {
            int c = ch * 5 + cc;
            u64 h0 = __ballot(v0 == c);
            u64 h1 = __ballot(v1 == c);
            if (lane == 0)
                *reinterpret_cast<uint4*>(&dout_p[cc][r][0]) =
                    make_uint4((u32)h0, (u32)(h0 >> 32), (u32)h1, (u32)(h1 >> 32));
        }
    }
    __syncthreads();

    // compute: dyIdx = t>>4, y = t&15; 176 active threads
    float acc[11];
    #pragma unroll
    for (int i = 0; i < 11; i++) acc[i] = 0.f;

    if (t < 176) {
        int dyIdx = t >> 4;
        int y     = t & 15;
        int r     = y - dyIdx + 10;          // in [0,25]

        #pragma unroll
        for (int cc = 0; cc < 5; cc++) {
            const u32* dr = &din_p[cc][r][0];
            u32 d0 = dr[0], d1 = dr[1], d2 = dr[2], d3 = dr[3], d4 = dr[4];
            const u32* orw = &dout_p[cc][y][0];
            u32 o0 = orw[0], o1 = orw[1], o2 = orw[2], o3 = orw[3];
            float wgt = wexp5[cc];
            #pragma unroll
            for (int dxi = 0; dxi < 11; dxi++) {
                int k = 10 - dxi;
                u32 s0 = __builtin_amdgcn_alignbit(d1, d0, k);
                u32 s1 = __builtin_amdgcn_alignbit(d2, d1, k);
                u32 s2 = __builtin_amdgcn_alignbit(d3, d2, k);
                u32 s3 = __builtin_amdgcn_alignbit(d4, d3, k);
                int cnt = __popc(s0 & o0) + __popc(s1 & o1)
                        + __popc(s2 & o2) + __popc(s3 & o3);
                acc[dxi] += wgt * (float)cnt;
            }
        }
    }

    // reduce over the 16-lane y-group
    #pragma unroll
    for (int dxi = 0; dxi < 11; dxi++) {
        float v = acc[dxi];
        v += __shfl_down(v, 8, 16);
        v += __shfl_down(v, 4, 16);
        v += __shfl_down(v, 2, 16);
        v += __shfl_down(v, 1, 16);
        acc[dxi] = v;
    }
    if ((t & 15) == 0 && t < 176) {
        int dyIdx = t >> 4;
        #pragma unroll
        for (int dxi = 0; dxi < 11; dxi++) {
            int lin = dyIdx * 11 + dxi;
            if (lin == 60) continue;         // (0,0) excluded
            int s = lin - (lin > 60);
            mpart[(b * NS + s) * MSLOT + strip * 2 + ch] = acc[dxi];
        }
    }
}

// -------- kernel 2: fused softmax + A-table + MFMA (R8 body, 16-slot reduce) --------
__global__ __launch_bounds__(512) void accum_fused(
    const int* __restrict__ query_in, const float* __restrict__ mpart,
    const float* __restrict__ logit_scale, float* __restrict__ out)
{
    __shared__ u8  qs[AR][144];
    __shared__ float sm[NS];
    __shared__ unsigned short abf[128];
    __shared__ __align__(16) u32 Agl[11][64][4];

    int t  = threadIdx.x;
    int y0 = blockIdx.x * 8;
    int b  = blockIdx.y;
    const int* q = query_in + b * HW;

    u32 pk0 = 0, pk1 = 0;
    {
        int g = t;
        #pragma unroll
        for (int e = 0; e < 4; e++) {
            int idx = g * 4 + e;
            int r = idx / 144, p = idx - r * 144;
            int gy = y0 - 5 + r;
            bool ok = (gy >= 0) & (gy < H) & (p >= 5) & (p < 133);
            int cy = gy < 0 ? 0 : (gy > 127 ? 127 : gy);
            int cx = p < 5 ? 0 : (p > 132 ? 127 : p - 5);
            int v = q[cy * W + cx];
            pk0 |= (u32)(ok ? v : 0) << (8 * e);
        }
    }
    if (t < 648 - 512) {
        int g = t + 512;
        #pragma unroll
        for (int e = 0; e < 4; e++) {
            int idx = g * 4 + e;
            int r = idx / 144, p = idx - r * 144;
            int gy = y0 - 5 + r;
            bool ok = (gy >= 0) & (gy < H) & (p >= 5) & (p < 133);
            int cy = gy < 0 ? 0 : (gy > 127 ? 127 : gy);
            int cx = p < 5 ? 0 : (p > 132 ? 127 : p - 5);
            int v = q[cy * W + cx];
            pk1 |= (u32)(ok ? v : 0) << (8 * e);
        }
    }

    float scale = fminf(__expf(logit_scale[0]), 100.0f) * (1.0f / 128.0f);
    if (t < NS) {
        const float* mp = mpart + (t + b * NS) * MSLOT;
        float4 v0 = *reinterpret_cast<const float4*>(mp);
        float4 v1 = *reinterpret_cast<const float4*>(mp + 4);
        float4 v2 = *reinterpret_cast<const float4*>(mp + 8);
        float4 v3 = *reinterpret_cast<const float4*>(mp + 12);
        sm[t] = (v0.x + v0.y + v0.z + v0.w + v1.x + v1.y + v1.z + v1.w
               + v2.x + v2.y + v2.z + v2.w + v3.x + v3.y + v3.z + v3.w) * scale;
    }

    ((u32*)qs)[t] = pk0;
    if (t < 648 - 512) ((u32*)qs)[t + 512] = pk1;
    __syncthreads();

    if (t < 64) {
        float s0 = sm[t];
        float s1 = (t + 64 < NS) ? sm[t + 64] : -INFINITY;
        float m = fmaxf(s0, s1);
        for (int off = 32; off > 0; off >>= 1) m = fmaxf(m, __shfl_xor(m, off, 64));
        float e0 = __expf(s0 - m);
        float e1 = (t + 64 < NS) ? __expf(s1 - m) : 0.f;
        float sum = e0 + e1;
        for (int off = 32; off > 0; off >>= 1) sum += __shfl_xor(sum, off, 64);
        float inv = 1.0f / sum;
        sm[t] = e0 * inv;
        if (t + 64 < NS) sm[t + 64] = e1 * inv;
    }
    __syncthreads();
    if (t < 128) {
        unsigned short v = 0;
        if (t < 121 && t != 60) {
            int si = t - (t > 60);
            __hip_bfloat16 hb = __float2bfloat16(sm[si]);
            v = *reinterpret_cast<unsigned short*>(&hb);
        }
        abf[t] = v;
    }
    __syncthreads();

    {
        int e = t;
        int st = e >> 6, l = e & 63;
        int mrow = l & 15, g8 = (l >> 4) * 8;
        #pragma unroll
        for (int p = 0; p < 4; p++) {
            int j0 = mrow + 10 - (g8 + p * 2);
            int j1 = j0 - 1;
            int i0 = (j0 >= 0 && j0 <= 10) ? (10 - st) * 11 + j0 : 121;
            int i1 = (j1 >= 0 && j1 <= 10) ? (10 - st) * 11 + j1 : 121;
            Agl[st][l][p] = (u32)abf[i0] | ((u32)abf[i1] << 16);
        }
    }
    if (t < 704 - 512) {
        int e = t + 512;
        int st = e >> 6, l = e & 63;
        int mrow = l & 15, g8 = (l >> 4) * 8;
        #pragma unroll
        for (int p = 0; p < 4; p++) {
            int j0 = mrow + 10 - (g8 + p * 2);
            int j1 = j0 - 1;
            int i0 = (j0 >= 0 && j0 <= 10) ? (10 - st) * 11 + j0 : 121;
            int i1 = (j1 >= 0 && j1 <= 10) ? (10 - st) * 11 + j1 : 121;
            Agl[st][l][p] = (u32)abf[i0] | ((u32)abf[i1] << 16);
        }
    }
    __syncthreads();

    int lane = t & 63, w = t >> 6;
    int x0 = w * 16;
    int c = lane & 15, g = lane >> 4;

    #define BUILD_B(r) ({                                                        \
        u64 eight = *reinterpret_cast<const u64*>(&qs[(r)][x0 + 8 * g]);         \
        u32 lo = (u32)eight, hi = (u32)(eight >> 32);                            \
        u32 b0 = ((int)(lo & 255) == c ? 0x3F80u : 0u)                           \
               | ((int)((lo >> 8)  & 255) == c ? 0x3F800000u : 0u);              \
        u32 b1 = ((int)((lo >> 16) & 255) == c ? 0x3F80u : 0u)                   \
               | ((int)((lo >> 24) & 255) == c ? 0x3F800000u : 0u);              \
        u32 b2 = ((int)(hi & 255) == c ? 0x3F80u : 0u)                           \
               | ((int)((hi >> 8)  & 255) == c ? 0x3F800000u : 0u);              \
        u32 b3 = ((int)((hi >> 16) & 255) == c ? 0x3F80u : 0u)                   \
               | ((int)((hi >> 24) & 255) == c ? 0x3F800000u : 0u);              \
        make_uint4(b0, b1, b2, b3); })

    uint4 bf[8];
    #pragma unroll
    for (int r = 0; r < 7; r++) bf[r & 7] = BUILD_B(r);

    f32x4 acc0[4], acc1[4];
    #pragma unroll
    for (int j = 0; j < 4; j++) { acc0[j] = (f32x4){0,0,0,0}; acc1[j] = (f32x4){0,0,0,0}; }

    #pragma unroll
    for (int st = 0; st < 11; st++) {
        bf[(st + 7) & 7] = BUILD_B(st + 7);
        uint4 a4 = *reinterpret_cast<const uint4*>(&Agl[st][lane][0]);
        union { uint4 u; bf16x8 v; } A; A.u = a4;
        #pragma unroll
        for (int j = 0; j < 4; j++) {
            union { uint4 u; bf16x8 v; } B0, B1;
            B0.u = bf[(st + j) & 7];
            B1.u = bf[(st + 4 + j) & 7];
            acc0[j] = __builtin_amdgcn_mfma_f32_16x16x32_bf16(A.v, B0.v, acc0[j], 0, 0, 0);
            acc1[j] = __builtin_amdgcn_mfma_f32_16x16x32_bf16(A.v, B1.v, acc1[j], 0, 0, 0);
        }
    }
    #undef BUILD_B

    if (c < COLORS) {
        #pragma unroll
        for (int j = 0; j < 4; j++) {
            float* ob0 = out + (((size_t)b * COLORS + c) * H + (y0 + j)) * W + x0 + 4 * g;
            float4 r0;
            r0.x = __logf(fmaxf(acc0[j][0], 1e-6f));
            r0.y = __logf(fmaxf(acc0[j][1], 1e-6f));
            r0.z = __logf(fmaxf(acc0[j][2], 1e-6f));
            r0.w = __logf(fmaxf(acc0[j][3], 1e-6f));
            *reinterpret_cast<float4*>(ob0) = r0;
            float* ob1 = out + (((size_t)b * COLORS + c) * H + (y0 + 4 + j)) * W + x0 + 4 * g;
            float4 r1;
            r1.x = __logf(fmaxf(acc1[j][0], 1e-6f));
            r1.y = __logf(fmaxf(acc1[j][1], 1e-6f));
            r1.z = __logf(fmaxf(acc1[j][2], 1e-6f));
            r1.w = __logf(fmaxf(acc1[j][3], 1e-6f));
            *reinterpret_cast<float4*>(ob1) = r1;
        }
    }
}

// ----------------------- legacy fallback (tiny ws) -----------------------
__global__ __launch_bounds__(256) void match_kernel(
    const int* __restrict__ demo_in, const int* __restrict__ demo_out,
    const float* __restrict__ clw, float* __restrict__ match)
{
    int blk = blockIdx.x;
    int b = blk / NS;
    int s = blk % NS;
    int lin = s + (s >= 60 ? 1 : 0);
    int dy = lin / 11 - 5, dx = lin % 11 - 5;

    __shared__ float wexp[COLORS];
    int tid = threadIdx.x;
    if (tid < COLORS) wexp[tid] = expf(clw[tid]);
    __syncthreads();

    const int* __restrict__ din  = demo_in  + b * HW;
    const int* __restrict__ dout = demo_out + b * HW;

    float partial = 0.f;
    for (int i = tid; i < HW; i += 256) {
        int yy = i >> 7, xx = i & 127;
        int co = dout[i];
        int sy = yy - dy, sx = xx - dx;
        int v = 0;
        if (sy >= 0 && sy < H && sx >= 0 && sx < W) v = din[sy * W + sx];
        if (v == co) partial += wexp[co];
    }
    for (int off = 32; off > 0; off >>= 1) partial += __shfl_down(partial, off, 64);
    __shared__ float wsum[4];
    if ((tid & 63) == 0) wsum[tid >> 6] = partial;
    __syncthreads();
    if (tid == 0) match[blk] = wsum[0] + wsum[1] + wsum[2] + wsum[3];
}

__global__ __launch_bounds__(64) void softmax_kernel(
    const float* __restrict__ match, const float* __restrict__ logit_scale,
    float* __restrict__ attention)
{
    int b = blockIdx.x;
    int lane = threadIdx.x;
    float scale = fminf(expf(logit_scale[0]), 100.0f) / sqrtf((float)HW);
    int i0 = lane, i1 = lane + 64;
    float s0 = match[b * NS + i0] * scale;
    float s1 = (i1 < NS) ? match[b * NS + i1] * scale : -INFINITY;
    float m = fmaxf(s0, s1);
    for (int off = 32; off > 0; off >>= 1) m = fmaxf(m, __shfl_xor(m, off, 64));
    float e0 = expf(s0 - m);
    float e1 = (i1 < NS) ? expf(s1 - m) : 0.f;
    float sum = e0 + e1;
    for (int off = 32; off > 0; off >>= 1) sum += __shfl_xor(sum, off, 64);
    float inv = 1.0f / sum;
    attention[b * NS + i0] = e0 * inv;
    if (i1 < NS) attention[b * NS + i1] = e1 * inv;
}

__global__ __launch_bounds__(128) void accum_kernel(
    const int* __restrict__ query_in, const float* __restrict__ attention,
    float* __restrict__ out)
{
    int blk = blockIdx.x;
    int b = blk >> 7;
    int y = blk & 127;
    int x = threadIdx.x;

    __shared__ float att[NS];
    if (threadIdx.x < NS) att[threadIdx.x] = attention[b * NS + threadIdx.x];
    __syncthreads();

    const int* __restrict__ q = query_in + b * HW;
    float acc[COLORS];
    #pragma unroll
    for (int c = 0; c < COLORS; c++) acc[c] = 0.f;

    #pragma unroll 4
    for (int s = 0; s < NS; s++) {
        int lin = s + (s >= 60 ? 1 : 0);
        int dy = lin / 11 - 5, dx = lin % 11 - 5;
        int sy = y - dy, sx = x - dx;
        int v = 0;
        if (sy >= 0 && sy < H && sx >= 0 && sx < W) v = q[sy * W + sx];
        float a = att[s];
        #pragma unroll
        for (int c = 0; c < COLORS; c++) acc[c] += (v == c) ? a : 0.f;
    }
    float* __restrict__ ob = out + (size_t)b * COLORS * HW + y * W + x;
    #pragma unroll
    for (int c = 0; c < COLORS; c++) ob[c * HW] = __logf(fmaxf(acc[c], 1e-6f));
}

extern "C" void kernel_launch(void* const* d_in, const int* in_sizes, int n_in,
                              void* d_out, int out_size, void* d_ws, size_t ws_size,
                              hipStream_t stream) {
    const int*   demo_in     = (const int*)d_in[0];
    const int*   demo_out    = (const int*)d_in[1];
    const int*   query_in    = (const int*)d_in[2];
    const float* clw         = (const float*)d_in[3];
    const float* logit_scale = (const float*)d_in[4];
    float* out = (float*)d_out;

    size_t needed = (size_t)NB * NS * MSLOT * sizeof(float);   // 245760 B

    if (ws_size >= needed) {
        float* mpart = (float*)d_ws;
        match_strip<<<dim3(8, NB * 2), 512, 0, stream>>>(demo_in, demo_out, clw, mpart);
        accum_fused<<<dim3(H / 8, NB), 512, 0, stream>>>(query_in, mpart, logit_scale, out);
    } else {
        float* match = (float*)d_ws;
        float* att   = match + NB * NS;
        match_kernel<<<NB * NS, 256, 0, stream>>>(demo_in, demo_out, clw, match);
        softmax_kernel<<<NB, 64, 0, stream>>>(match, logit_scale, att);
        accum_kernel<<<NB * H, 128, 0, stream>>>(query_in, att, out);
    }
}

// Round 15
// 28.342 us; speedup vs baseline: 1.6877x; 1.1640x over previous
//
#include <hip/hip_runtime.h>
#include <hip/hip_bf16.h>
#include <math.h>

#define COLORS 10
#define NB 32
#define H 128
#define W 128
#define NS 120          // 11*11 - 1 shifts
#define HW (H*W)
#define STRIPS 8
#define SH 16           // rows per strip (match kernel)
#define DROWS 26        // SH + 10 padded rows
#define DINW 12         // padded D row stride in u32 (48B, bank-staggered)
#define AR 18           // accum staged rows (8-row tile + 10)

typedef unsigned char u8;
typedef unsigned int u32;
typedef unsigned long long u64;
typedef float f32x4 __attribute__((ext_vector_type(4)));
typedef short bf16x8 __attribute__((ext_vector_type(8)));

// ---------------- kernel 1: per-(b,strip) bitplane popcount match ----------------
// R8 structure; build loads batched (issued back-to-back before ballot passes).
__global__ __launch_bounds__(512) void match_strip(
    const int* __restrict__ demo_in, const int* __restrict__ demo_out,
    const float* __restrict__ clw, float* __restrict__ mpart)
{
    __shared__ __align__(16) u32 din_p[COLORS][DROWS][DINW];   // 12480 B
    __shared__ __align__(16) u32 dout_p[COLORS][SH][4];        // 2560 B
    __shared__ float wexp[COLORS];

    int t = threadIdx.x;
    int strip = blockIdx.x;
    int b = blockIdx.y;
    int wave = t >> 6, lane = t & 63;
    int y0 = strip * SH;

    if (t < COLORS) wexp[t] = __expf(clw[t]);

    const int* di = demo_in  + b * HW;
    const int* dd = demo_out + b * HW;

    // ---- batched load phase: all row loads issued before any ballot ----
    int vv0[4], vv1[4];
    bool okk[4];
    #pragma unroll
    for (int i = 0; i < 4; i++) {
        int r = wave + i * 8;
        int gy = y0 - 5 + r;
        bool ok = (r < DROWS) && (gy >= 0 && gy < H);
        int cy = (gy < 0) ? 0 : (gy > 127 ? 127 : gy);
        vv0[i] = di[cy * W + lane];          // clamped address, always issued
        vv1[i] = di[cy * W + 64 + lane];
        okk[i] = ok;
    }
    int w0[2], w1[2];
    #pragma unroll
    for (int i = 0; i < 2; i++) {
        int r = wave + i * 8;
        int gy = y0 + r;                     // always in [0,127]
        w0[i] = dd[gy * W + lane];
        w1[i] = dd[gy * W + 64 + lane];
    }

    // ---- ballot/build passes (consume batched registers) ----
    #pragma unroll
    for (int i = 0; i < 4; i++) {
        int r = wave + i * 8;
        if (r < DROWS) {
            bool ok = okk[i];
            int v0 = ok ? vv0[i] : 0;
            int v1 = ok ? vv1[i] : 0;
            #pragma unroll
            for (int c = 0; c < COLORS; c++) {
                u64 h0 = __ballot(v0 == c);
                u64 h1 = __ballot(v1 == c);
                u64 P0, P1, P2;
                if (!ok) {
                    P0 = (c == 0) ? ~0ull : 0ull;
                    P1 = P0;
                    P2 = (c == 0) ? 0x3FFull : 0ull;
                } else {
                    u64 lm = (c == 0) ? 0x1Full  : 0ull;
                    u64 rm = (c == 0) ? 0x3E0ull : 0ull;
                    P0 = (h0 << 5) | lm;
                    P1 = (h0 >> 59) | (h1 << 5);
                    P2 = (h1 >> 59) | rm;
                }
                if (lane == 0) {
                    *reinterpret_cast<uint4*>(&din_p[c][r][0]) =
                        make_uint4((u32)P0, (u32)(P0 >> 32), (u32)P1, (u32)(P1 >> 32));
                    *reinterpret_cast<uint4*>(&din_p[c][r][4]) =
                        make_uint4((u32)P2, 0u, 0u, 0u);
                }
            }
        }
    }
    #pragma unroll
    for (int i = 0; i < 2; i++) {
        int r = wave + i * 8;
        int v0 = w0[i], v1 = w1[i];
        #pragma unroll
        for (int c = 0; c < COLORS; c++) {
            u64 h0 = __ballot(v0 == c);
            u64 h1 = __ballot(v1 == c);
            if (lane == 0)
                *reinterpret_cast<uint4*>(&dout_p[c][r][0]) =
                    make_uint4((u32)h0, (u32)(h0 >> 32), (u32)h1, (u32)(h1 >> 32));
        }
    }
    __syncthreads();

    // ---- compute: t = s*4 + qq, each thread 4 rows (R8 verbatim) ----
    int s = t >> 2, qq = t & 3;
    float acc = 0.f;
    if (t < 4 * NS) {
        int lin = s + (s >= 60);
        int dy = lin / 11 - 5, dx = lin % 11 - 5;
        int k = 5 - dx;
        for (int c = 0; c < COLORS; c++) {
            int cnt = 0;
            #pragma unroll
            for (int yy = 0; yy < 4; yy++) {
                int y = qq * 4 + yy;
                int r = y - dy + 5;                 // 0..25
                const u32* dr   = &din_p[c][r][0];
                const u32* orow = &dout_p[c][y][0];
                u32 s0 = __builtin_amdgcn_alignbit(dr[1], dr[0], k);
                u32 s1 = __builtin_amdgcn_alignbit(dr[2], dr[1], k);
                u32 s2 = __builtin_amdgcn_alignbit(dr[3], dr[2], k);
                u32 s3 = __builtin_amdgcn_alignbit(dr[4], dr[3], k);
                cnt += __popc(s0 & orow[0]) + __popc(s1 & orow[1])
                     + __popc(s2 & orow[2]) + __popc(s3 & orow[3]);
            }
            acc += wexp[c] * (float)cnt;
        }
    }
    acc += __shfl_down(acc, 1, 64);
    acc += __shfl_down(acc, 2, 64);
    if (qq == 0 && t < 4 * NS)
        mpart[(b * NS + s) * STRIPS + strip] = acc;
}

// -------- kernel 2: fused softmax + shared A-table + MFMA (R8 verbatim) --------
__global__ __launch_bounds__(512) void accum_fused(
    const int* __restrict__ query_in, const float* __restrict__ mpart,
    const float* __restrict__ logit_scale, float* __restrict__ out)
{
    __shared__ u8  qs[AR][144];                    // 2592 B, byte colors
    __shared__ float sm[NS];
    __shared__ unsigned short abf[128];            // bf16 att by lin; 60,121..127 = 0
    __shared__ __align__(16) u32 Agl[11][64][4];   // A-fragments, 11264 B

    int t  = threadIdx.x;
    int y0 = blockIdx.x * 8;
    int b  = blockIdx.y;
    const int* q = query_in + b * HW;

    u32 pk0 = 0, pk1 = 0;
    {
        int g = t;
        #pragma unroll
        for (int e = 0; e < 4; e++) {
            int idx = g * 4 + e;
            int r = idx / 144, p = idx - r * 144;
            int gy = y0 - 5 + r;
            bool ok = (gy >= 0) & (gy < H) & (p >= 5) & (p < 133);
            int cy = gy < 0 ? 0 : (gy > 127 ? 127 : gy);
            int cx = p < 5 ? 0 : (p > 132 ? 127 : p - 5);
            int v = q[cy * W + cx];
            pk0 |= (u32)(ok ? v : 0) << (8 * e);
        }
    }
    if (t < 648 - 512) {
        int g = t + 512;
        #pragma unroll
        for (int e = 0; e < 4; e++) {
            int idx = g * 4 + e;
            int r = idx / 144, p = idx - r * 144;
            int gy = y0 - 5 + r;
            bool ok = (gy >= 0) & (gy < H) & (p >= 5) & (p < 133);
            int cy = gy < 0 ? 0 : (gy > 127 ? 127 : gy);
            int cx = p < 5 ? 0 : (p > 132 ? 127 : p - 5);
            int v = q[cy * W + cx];
            pk1 |= (u32)(ok ? v : 0) << (8 * e);
        }
    }

    float scale = fminf(__expf(logit_scale[0]), 100.0f) * (1.0f / 128.0f);
    if (t < NS) {
        const float* mp = mpart + (t + b * NS) * STRIPS;
        float4 v0 = *reinterpret_cast<const float4*>(mp);
        float4 v1 = *reinterpret_cast<const float4*>(mp + 4);
        sm[t] = (v0.x + v0.y + v0.z + v0.w + v1.x + v1.y + v1.z + v1.w) * scale;
    }

    ((u32*)qs)[t] = pk0;
    if (t < 648 - 512) ((u32*)qs)[t + 512] = pk1;
    __syncthreads();

    if (t < 64) {
        float s0 = sm[t];
        float s1 = (t + 64 < NS) ? sm[t + 64] : -INFINITY;
        float m = fmaxf(s0, s1);
        for (int off = 32; off > 0; off >>= 1) m = fmaxf(m, __shfl_xor(m, off, 64));
        float e0 = __expf(s0 - m);
        float e1 = (t + 64 < NS) ? __expf(s1 - m) : 0.f;
        float sum = e0 + e1;
        for (int off = 32; off > 0; off >>= 1) sum += __shfl_xor(sum, off, 64);
        float inv = 1.0f / sum;
        sm[t] = e0 * inv;
        if (t + 64 < NS) sm[t + 64] = e1 * inv;
    }
    __syncthreads();
    if (t < 128) {
        unsigned short v = 0;
        if (t < 121 && t != 60) {
            int si = t - (t > 60);
            __hip_bfloat16 hb = __float2bfloat16(sm[si]);
            v = *reinterpret_cast<unsigned short*>(&hb);
        }
        abf[t] = v;
    }
    __syncthreads();

    {
        int e = t;
        int st = e >> 6, l = e & 63;
        int mrow = l & 15, g8 = (l >> 4) * 8;
        #pragma unroll
        for (int p = 0; p < 4; p++) {
            int j0 = mrow + 10 - (g8 + p * 2);
            int j1 = j0 - 1;
            int i0 = (j0 >= 0 && j0 <= 10) ? (10 - st) * 11 + j0 : 121;
            int i1 = (j1 >= 0 && j1 <= 10) ? (10 - st) * 11 + j1 : 121;
            Agl[st][l][p] = (u32)abf[i0] | ((u32)abf[i1] << 16);
        }
    }
    if (t < 704 - 512) {
        int e = t + 512;
        int st = e >> 6, l = e & 63;
        int mrow = l & 15, g8 = (l >> 4) * 8;
        #pragma unroll
        for (int p = 0; p < 4; p++) {
            int j0 = mrow + 10 - (g8 + p * 2);
            int j1 = j0 - 1;
            int i0 = (j0 >= 0 && j0 <= 10) ? (10 - st) * 11 + j0 : 121;
            int i1 = (j1 >= 0 && j1 <= 10) ? (10 - st) * 11 + j1 : 121;
            Agl[st][l][p] = (u32)abf[i0] | ((u32)abf[i1] << 16);
        }
    }
    __syncthreads();

    int lane = t & 63, w = t >> 6;
    int x0 = w * 16;
    int c = lane & 15, g = lane >> 4;

    #define BUILD_B(r) ({                                                        \
        u64 eight = *reinterpret_cast<const u64*>(&qs[(r)][x0 + 8 * g]);         \
        u32 lo = (u32)eight, hi = (u32)(eight >> 32);                            \
        u32 b0 = ((int)(lo & 255) == c ? 0x3F80u : 0u)                           \
               | ((int)((lo >> 8)  & 255) == c ? 0x3F800000u : 0u);              \
        u32 b1 = ((int)((lo >> 16) & 255) == c ? 0x3F80u : 0u)                   \
               | ((int)((lo >> 24) & 255) == c ? 0x3F800000u : 0u);              \
        u32 b2 = ((int)(hi & 255) == c ? 0x3F80u : 0u)                           \
               | ((int)((hi >> 8)  & 255) == c ? 0x3F800000u : 0u);              \
        u32 b3 = ((int)((hi >> 16) & 255) == c ? 0x3F80u : 0u)                   \
               | ((int)((hi >> 24) & 255) == c ? 0x3F800000u : 0u);              \
        make_uint4(b0, b1, b2, b3); })

    uint4 bf[8];
    #pragma unroll
    for (int r = 0; r < 7; r++) bf[r & 7] = BUILD_B(r);

    f32x4 acc0[4], acc1[4];
    #pragma unroll
    for (int j = 0; j < 4; j++) { acc0[j] = (f32x4){0,0,0,0}; acc1[j] = (f32x4){0,0,0,0}; }

    #pragma unroll
    for (int st = 0; st < 11; st++) {
        bf[(st + 7) & 7] = BUILD_B(st + 7);
        uint4 a4 = *reinterpret_cast<const uint4*>(&Agl[st][lane][0]);
        union { uint4 u; bf16x8 v; } A; A.u = a4;
        #pragma unroll
        for (int j = 0; j < 4; j++) {
            union { uint4 u; bf16x8 v; } B0, B1;
            B0.u = bf[(st + j) & 7];
            B1.u = bf[(st + 4 + j) & 7];
            acc0[j] = __builtin_amdgcn_mfma_f32_16x16x32_bf16(A.v, B0.v, acc0[j], 0, 0, 0);
            acc1[j] = __builtin_amdgcn_mfma_f32_16x16x32_bf16(A.v, B1.v, acc1[j], 0, 0, 0);
        }
    }
    #undef BUILD_B

    if (c < COLORS) {
        #pragma unroll
        for (int j = 0; j < 4; j++) {
            float* ob0 = out + (((size_t)b * COLORS + c) * H + (y0 + j)) * W + x0 + 4 * g;
            float4 r0;
            r0.x = __logf(fmaxf(acc0[j][0], 1e-6f));
            r0.y = __logf(fmaxf(acc0[j][1], 1e-6f));
            r0.z = __logf(fmaxf(acc0[j][2], 1e-6f));
            r0.w = __logf(fmaxf(acc0[j][3], 1e-6f));
            *reinterpret_cast<float4*>(ob0) = r0;
            float* ob1 = out + (((size_t)b * COLORS + c) * H + (y0 + 4 + j)) * W + x0 + 4 * g;
            float4 r1;
            r1.x = __logf(fmaxf(acc1[j][0], 1e-6f));
            r1.y = __logf(fmaxf(acc1[j][1], 1e-6f));
            r1.z = __logf(fmaxf(acc1[j][2], 1e-6f));
            r1.w = __logf(fmaxf(acc1[j][3], 1e-6f));
            *reinterpret_cast<float4*>(ob1) = r1;
        }
    }
}

// ----------------------- legacy fallback (tiny ws) -----------------------
__global__ __launch_bounds__(256) void match_kernel(
    const int* __restrict__ demo_in, const int* __restrict__ demo_out,
    const float* __restrict__ clw, float* __restrict__ match)
{
    int blk = blockIdx.x;
    int b = blk / NS;
    int s = blk % NS;
    int lin = s + (s >= 60 ? 1 : 0);
    int dy = lin / 11 - 5, dx = lin % 11 - 5;

    __shared__ float wexp[COLORS];
    int tid = threadIdx.x;
    if (tid < COLORS) wexp[tid] = expf(clw[tid]);
    __syncthreads();

    const int* __restrict__ din  = demo_in  + b * HW;
    const int* __restrict__ dout = demo_out + b * HW;

    float partial = 0.f;
    for (int i = tid; i < HW; i += 256) {
        int yy = i >> 7, xx = i & 127;
        int co = dout[i];
        int sy = yy - dy, sx = xx - dx;
        int v = 0;
        if (sy >= 0 && sy < H && sx >= 0 && sx < W) v = din[sy * W + sx];
        if (v == co) partial += wexp[co];
    }
    for (int off = 32; off > 0; off >>= 1) partial += __shfl_down(partial, off, 64);
    __shared__ float wsum[4];
    if ((tid & 63) == 0) wsum[tid >> 6] = partial;
    __syncthreads();
    if (tid == 0) match[blk] = wsum[0] + wsum[1] + wsum[2] + wsum[3];
}

__global__ __launch_bounds__(64) void softmax_kernel(
    const float* __restrict__ match, const float* __restrict__ logit_scale,
    float* __restrict__ attention)
{
    int b = blockIdx.x;
    int lane = threadIdx.x;
    float scale = fminf(expf(logit_scale[0]), 100.0f) / sqrtf((float)HW);
    int i0 = lane, i1 = lane + 64;
    float s0 = match[b * NS + i0] * scale;
    float s1 = (i1 < NS) ? match[b * NS + i1] * scale : -INFINITY;
    float m = fmaxf(s0, s1);
    for (int off = 32; off > 0; off >>= 1) m = fmaxf(m, __shfl_xor(m, off, 64));
    float e0 = expf(s0 - m);
    float e1 = (i1 < NS) ? expf(s1 - m) : 0.f;
    float sum = e0 + e1;
    for (int off = 32; off > 0; off >>= 1) sum += __shfl_xor(sum, off, 64);
    float inv = 1.0f / sum;
    attention[b * NS + i0] = e0 * inv;
    if (i1 < NS) attention[b * NS + i1] = e1 * inv;
}

__global__ __launch_bounds__(128) void accum_kernel(
    const int* __restrict__ query_in, const float* __restrict__ attention,
    float* __restrict__ out)
{
    int blk = blockIdx.x;
    int b = blk >> 7;
    int y = blk & 127;
    int x = threadIdx.x;

    __shared__ float att[NS];
    if (threadIdx.x < NS) att[threadIdx.x] = attention[b * NS + threadIdx.x];
    __syncthreads();

    const int* __restrict__ q = query_in + b * HW;
    float acc[COLORS];
    #pragma unroll
    for (int c = 0; c < COLORS; c++) acc[c] = 0.f;

    #pragma unroll 4
    for (int s = 0; s < NS; s++) {
        int lin = s + (s >= 60 ? 1 : 0);
        int dy = lin / 11 - 5, dx = lin % 11 - 5;
        int sy = y - dy, sx = x - dx;
        int v = 0;
        if (sy >= 0 && sy < H && sx >= 0 && sx < W) v = q[sy * W + sx];
        float a = att[s];
        #pragma unroll
        for (int c = 0; c < COLORS; c++) acc[c] += (v == c) ? a : 0.f;
    }
    float* __restrict__ ob = out + (size_t)b * COLORS * HW + y * W + x;
    #pragma unroll
    for (int c = 0; c < COLORS; c++) ob[c * HW] = __logf(fmaxf(acc[c], 1e-6f));
}

extern "C" void kernel_launch(void* const* d_in, const int* in_sizes, int n_in,
                              void* d_out, int out_size, void* d_ws, size_t ws_size,
                              hipStream_t stream) {
    const int*   demo_in     = (const int*)d_in[0];
    const int*   demo_out    = (const int*)d_in[1];
    const int*   query_in    = (const int*)d_in[2];
    const float* clw         = (const float*)d_in[3];
    const float* logit_scale = (const float*)d_in[4];
    float* out = (float*)d_out;

    size_t needed = (size_t)NB * NS * STRIPS * sizeof(float);   // 122880 B

    if (ws_size >= needed) {
        float* mpart = (float*)d_ws;
        match_strip<<<dim3(STRIPS, NB), 512, 0, stream>>>(demo_in, demo_out, clw, mpart);
        accum_fused<<<dim3(H / 8, NB), 512, 0, stream>>>(query_in, mpart, logit_scale, out);
    } else {
        float* match = (float*)d_ws;
        float* att   = match + NB * NS;
        match_kernel<<<NB * NS, 256, 0, stream>>>(demo_in, demo_out, clw, match);
        softmax_kernel<<<NB, 64, 0, stream>>>(match, logit_scale, att);
        accum_kernel<<<NB * H, 128, 0, stream>>>(query_in, att, out);
    }
}